// Round 8
// baseline (9808.025 us; speedup 1.0000x reference)
//
#include <hip/hip_runtime.h>

#define NR 4096
#define NT 720
#define TSEC 3600.0f
#define QLB 1e-4f
#define COLS_MAX 32768
#define NBLK 64

// ---------------- CSR build: count ----------------
__global__ void count_kernel(const float* __restrict__ adj, int* __restrict__ cnt) {
    int row = blockIdx.x;
    int lane = threadIdx.x;
    const float* r = adj + (size_t)row * NR;
    int c = 0;
    for (int base = 0; base < NR; base += 64) {
        float v = r[base + lane];
        unsigned long long m = __ballot(v != 0.0f);
        c += __popcll(m);
    }
    if (lane == 0) cnt[row] = c;
}

// ---------------- exclusive scan (single block, 1024 thr, 4/thread) ----------------
__global__ void scan_kernel(const int* __restrict__ cnt, int* __restrict__ rowptr) {
    __shared__ int part[1024];
    int tid = threadIdx.x;
    int base = tid * 4;
    int s0 = cnt[base], s1 = cnt[base + 1], s2 = cnt[base + 2], s3 = cnt[base + 3];
    int tot = s0 + s1 + s2 + s3;
    part[tid] = tot;
    __syncthreads();
    for (int off = 1; off < 1024; off <<= 1) {
        int v = part[tid];
        int add = (tid >= off) ? part[tid - off] : 0;
        __syncthreads();
        part[tid] = v + add;
        __syncthreads();
    }
    int excl = (tid > 0) ? part[tid - 1] : 0;
    rowptr[base]     = excl;
    rowptr[base + 1] = excl + s0;
    rowptr[base + 2] = excl + s0 + s1;
    rowptr[base + 3] = excl + s0 + s1 + s2;
    if (tid == 1023) rowptr[NR] = excl + tot;
}

// ---------------- CSR build: fill (original col indices, ascending) ----------------
__global__ void fill_kernel(const float* __restrict__ adj,
                            const int* __restrict__ rowptr, int* __restrict__ cols) {
    int row = blockIdx.x;
    int lane = threadIdx.x;
    const float* r = adj + (size_t)row * NR;
    int wbase = rowptr[row];
    for (int base = 0; base < NR; base += 64) {
        float v = r[base + lane];
        unsigned long long m = __ballot(v != 0.0f);
        if (v != 0.0f) {
            int pos = __popcll(m & ((1ull << lane) - 1ull));
            cols[wbase + pos] = base + lane;
        }
        wbase += __popcll(m);
    }
}

// ---------------- DAG levels (monotone Jacobi to fixpoint) ----------------
__global__ void level_kernel(const int* __restrict__ rowptr,
                             const int* __restrict__ cols, int* __restrict__ level_g) {
    __shared__ int lev[NR];
    __shared__ int changed;
    int tid = threadIdx.x;
#pragma unroll
    for (int k = 0; k < 4; k++) lev[tid + k * 1024] = 0;
    __syncthreads();
    for (int iter = 0; iter < NR; ++iter) {
        if (tid == 0) changed = 0;
        __syncthreads();
#pragma unroll
        for (int k = 0; k < 4; k++) {
            int i = tid + k * 1024;
            int b0 = rowptr[i], b1 = rowptr[i + 1];
            int m = 0;
            for (int e = b0; e < b1; e++) {
                int l = lev[cols[e]] + 1;
                m = (l > m) ? l : m;
            }
            if (b1 > b0 && m != lev[i]) { lev[i] = m; changed = 1; }
        }
        __syncthreads();
        if (changed == 0) break;
        __syncthreads();
    }
#pragma unroll
    for (int k = 0; k < 4; k++) level_g[tid + k * 1024] = lev[tid + k * 1024];
}

// ---------------- level sort: bitonic on (level<<12 | row), deterministic ----------------
__global__ void sort_kernel(const int* __restrict__ level_g,
                            int* __restrict__ perm, int* __restrict__ lev_p,
                            int* __restrict__ meta) {
    __shared__ int keys[NR];
    int tid = threadIdx.x;
#pragma unroll
    for (int m = 0; m < 4; m++) {
        int i = tid + m * 1024;
        keys[i] = (level_g[i] << 12) | i;
    }
    __syncthreads();
    for (int ks = 2; ks <= NR; ks <<= 1) {
        for (int j = ks >> 1; j >= 1; j >>= 1) {
#pragma unroll
            for (int m = 0; m < 4; m++) {
                int i = tid + m * 1024;
                int p = i ^ j;
                if (p > i) {
                    bool up = ((i & ks) == 0);
                    int a = keys[i], b = keys[p];
                    if (up ? (a > b) : (a < b)) { keys[i] = b; keys[p] = a; }
                }
            }
            __syncthreads();
        }
    }
#pragma unroll
    for (int m = 0; m < 4; m++) {
        int p = tid + m * 1024;
        int key = keys[p];
        perm[p] = key & (NR - 1);
        lev_p[p] = key >> 12;
        if (p == NR - 1) meta[0] = key >> 12;  // max level
    }
}

// ---------------- prep: lstart[] binary searches + zero grid-barrier vars ----------------
__global__ void prep_kernel(const int* __restrict__ lev_p, int* __restrict__ lstart,
                            int* __restrict__ bar) {
    int tid = threadIdx.x;
    if (tid < 136) {
        int lo = 0, hi = NR;
        while (lo < hi) { int mid = (lo + hi) >> 1; if (lev_p[mid] < tid) lo = mid + 1; else hi = mid; }
        lstart[tid] = lo;
    }
    if (tid == 0) { bar[0] = 0; bar[1] = 0; }
}

// ---------------- coefficients (ORIGINAL row indexing) ----------------
__global__ void coef_kernel(const float* __restrict__ raw_n,
                            const float* __restrict__ raw_q,
                            const float* __restrict__ raw_p,
                            const float* __restrict__ width,
                            const float* __restrict__ length,
                            const float* __restrict__ slope,
                            const float* __restrict__ x_storage,
                            float* __restrict__ c1, float* __restrict__ c2,
                            float* __restrict__ c3, float* __restrict__ c4) {
    int i = blockIdx.x * blockDim.x + threadIdx.x;
    if (i >= NR) return;
    float n   = 0.01f + raw_n[i] * (0.3f - 0.01f);
    float qsp = 1.5f + raw_q[i] * (3.0f - 1.5f);
    float psp = 0.5f + raw_p[i] * (2.0f - 0.5f);
    float s0  = fmaxf(slope[i], 1e-4f);
    float depth = logf(width[i] / psp) / logf(qsp);
    float v = (1.0f / n) * powf(depth, 2.0f / 3.0f) * sqrtf(s0);
    float c = fminf(fmaxf(v, 0.3f), 15.0f) * (5.0f / 3.0f);
    float k = length[i] / c;
    float x = x_storage[0];
    float denom = 2.0f * k * (1.0f - x) + TSEC;
    c1[i] = (TSEC - 2.0f * k * x) / denom;
    c2[i] = (TSEC + 2.0f * k * x) / denom;
    c3[i] = (2.0f * k * (1.0f - x) - TSEC) / denom;
    c4[i] = 2.0f * TSEC / denom;
}

// ---------------- grid barrier (sense-reversing, 64 co-resident blocks) ----------------
__device__ __forceinline__ void gbar(int* bar, int* lsense_p) {
    __threadfence();
    __syncthreads();
    if (threadIdx.x == 0) {
        int ls = *lsense_p ^ 1;
        *lsense_p = ls;
        int prev = __hip_atomic_fetch_add(&bar[0], 1, __ATOMIC_ACQ_REL,
                                          __HIP_MEMORY_SCOPE_AGENT);
        if (prev == NBLK - 1) {
            __hip_atomic_store(&bar[0], 0, __ATOMIC_RELAXED, __HIP_MEMORY_SCOPE_AGENT);
            __hip_atomic_store(&bar[1], ls, __ATOMIC_RELEASE, __HIP_MEMORY_SCOPE_AGENT);
        } else {
            while (__hip_atomic_load(&bar[1], __ATOMIC_ACQUIRE,
                                     __HIP_MEMORY_SCOPE_AGENT) != ls)
                __builtin_amdgcn_s_sleep(2);
        }
    }
    __syncthreads();
    __threadfence();
}

// ---------------- level-parallel trajectory solver ----------------
// X[i][s] layout: row-major trajectories, stride = TC+1; slot 0 = carry x(t0),
// slots 1..tc = times t0+1..t0+tc. Per chunk:
//   S1: slot0 <- carry (chunk0: raw d0 = q[0][i])
//   S2: X[i][s] = C4_i * clamp(q[t0+s-1][i])           (LDS-tiled transpose)
//   S3: for each level l: A) K-gather: X[i][s] += sum_p C2*clamp(X[p][s-1]) + C1*X[p][s]
//                         B) recurrence: x = C3*clamp(x) + X[i][s] (in place)
//   S4: out[t0+s] = clamp(X[NR-1][s]) (block 0)
// Exact reference semantics: clamp applied to carried state + q; in-solve
// parent values (C1 term) unclamped (verified R3-R7).
__global__ __launch_bounds__(256, 1) void solve_kernel(
    const float* __restrict__ qp, const float* __restrict__ c1g,
    const float* __restrict__ c2g, const float* __restrict__ c3g,
    const float* __restrict__ c4g, const int* __restrict__ rowptr,
    const int* __restrict__ cols, const int* __restrict__ perm,
    const int* __restrict__ meta, const int* __restrict__ lstart,
    int* __restrict__ bar, float* __restrict__ X, float* __restrict__ out,
    int TC, int NCH) {
    __shared__ float tile[64][65];
    __shared__ int lsense;
    int tid = threadIdx.x, bid = blockIdx.x;
    if (tid == 0) lsense = 0;
    __syncthreads();
    int maxlev = meta[0];
    if (maxlev > 133) maxlev = 133;   // safety (depth ~15-25 expected)
    int stride = TC + 1;
    const int nth = NBLK * 256;
    int gtid = bid * 256 + tid;
    int wave = gtid >> 6, lane = tid & 63;
    const int nwv = nth >> 6;

    for (int c = 0; c < NCH; c++) {
        int t0 = c * TC;
        int tc = (c == NCH - 1) ? (NT - 1 - t0) : TC;
        // S1: slot0 = carry
        for (int i = gtid; i < NR; i += nth)
            X[(size_t)i * stride] = (c == 0) ? qp[i] : X[(size_t)i * stride + TC];
        gbar(bar, &lsense);
        // S2: q-term init, tiled transpose (read q coalesced, write X coalesced)
        int nts = (tc + 63) >> 6;
        for (int tl = bid; tl < 64 * nts; tl += NBLK) {
            int ti = tl & 63, ts = tl >> 6;
            int i0 = ti << 6, s0 = ts << 6;
#pragma unroll
            for (int k = 0; k < 16; k++) {
                int r = (k << 2) + (tid >> 6);   // q-row offset (time)
                int cc = tid & 63;               // i offset
                int s = s0 + 1 + r;
                float v = 0.f;
                if (s <= tc) v = qp[(size_t)(t0 + s - 1) * NR + i0 + cc];
                tile[r][cc] = v;
            }
            __syncthreads();
#pragma unroll
            for (int k = 0; k < 16; k++) {
                int r = (k << 2) + (tid >> 6);   // i offset
                int cc = tid & 63;               // slot offset
                int s = s0 + 1 + cc;
                if (s <= tc)
                    X[(size_t)(i0 + r) * stride + s] =
                        c4g[i0 + r] * fmaxf(tile[cc][r], QLB);
            }
            __syncthreads();
        }
        gbar(bar, &lsense);
        // S3: levels
        for (int l = 0; l <= maxlev; l++) {
            int p0 = lstart[l], p1 = lstart[l + 1];
            int nrl = p1 - p0;
            // A: K-gather, one wave per row, lanes over t (coalesced)
            for (int rr = wave; rr < nrl; rr += nwv) {
                int i = perm[p0 + rr];
                int b0 = rowptr[i], n = rowptr[i + 1] - b0;
                if (n > 0) {
                    float C1 = c1g[i], C2 = c2g[i];
                    size_t xb = (size_t)i * stride;
                    for (int s = lane + 1; s <= tc; s += 64) {
                        float acc = X[xb + s];
                        for (int e = 0; e < n; e++) {
                            size_t pb = (size_t)cols[b0 + e] * stride + s;
                            float xpp = X[pb - 1];
                            float xpc = X[pb];
                            acc += C2 * fmaxf(xpp, QLB) + C1 * xpc;
                        }
                        X[xb + s] = acc;
                    }
                }
            }
            gbar(bar, &lsense);
            // B: scalar recurrence, one thread per row (in place)
            for (int rr = gtid; rr < nrl; rr += nth) {
                int i = perm[p0 + rr];
                float C3 = c3g[i];
                size_t xb = (size_t)i * stride;
                float x = X[xb];
                for (int s = 1; s <= tc; s++) {
                    x = C3 * fmaxf(x, QLB) + X[xb + s];
                    X[xb + s] = x;
                }
            }
            gbar(bar, &lsense);
        }
        // S4: chunk output (block 0); no write conflicts with other blocks here
        if (bid == 0) {
            size_t gb = (size_t)(NR - 1) * stride;
            for (int s = tid; s <= tc; s += 256) {
                if (s >= 1) out[t0 + s] = fmaxf(X[gb + s], QLB);
                else if (c == 0) out[0] = fmaxf(X[gb], QLB);
            }
        }
        gbar(bar, &lsense);
    }
}

extern "C" void kernel_launch(void* const* d_in, const int* in_sizes, int n_in,
                              void* d_out, int out_size, void* d_ws, size_t ws_size,
                              hipStream_t stream) {
    const float* q_prime  = (const float*)d_in[0];
    const float* raw_n    = (const float*)d_in[1];
    const float* raw_q    = (const float*)d_in[2];
    const float* raw_p    = (const float*)d_in[3];
    const float* width    = (const float*)d_in[4];
    const float* length   = (const float*)d_in[5];
    const float* slope    = (const float*)d_in[6];
    const float* adj      = (const float*)d_in[7];
    const float* x_stor   = (const float*)d_in[8];
    float* out = (float*)d_out;

    // workspace layout (4B elems)
    float* ws_f = (float*)d_ws;
    float* c1p = ws_f;                        // NR
    float* c2p = ws_f + NR;
    float* c3p = ws_f + 2 * NR;
    float* c4p = ws_f + 3 * NR;
    int* ws_i   = (int*)(ws_f + 4 * NR);
    int* cnt    = ws_i;                       // NR
    int* rowptr = cnt + NR;                   // NR+8
    int* cols   = rowptr + NR + 8;            // COLS_MAX
    int* level  = cols + COLS_MAX;            // NR
    int* perm   = level + NR;                 // NR
    int* lev_p  = perm + NR;                  // NR
    int* meta   = lev_p + NR;                 // 8
    int* lstart = meta + 8;                   // 136
    int* bar    = lstart + 136;               // 8
    int* endbase = bar + 8;

    size_t base_bytes = (size_t)((char*)endbase - (char*)d_ws);
    size_t xoff = (base_bytes + 255) & ~(size_t)255;
    long long avail = (long long)ws_size - (long long)xoff;
    int cap = (int)(avail / ((long long)NR * 4)) - 1;   // max slots-1 per row
    int TC = (cap > NT - 1) ? (NT - 1) : cap;
    if (TC < 1) TC = 1;                        // degenerate safety
    int NCH = (NT - 1 + TC - 1) / TC;
    float* X = (float*)((char*)d_ws + xoff);

    count_kernel<<<NR, 64, 0, stream>>>(adj, cnt);
    scan_kernel<<<1, 1024, 0, stream>>>(cnt, rowptr);
    fill_kernel<<<NR, 64, 0, stream>>>(adj, rowptr, cols);
    level_kernel<<<1, 1024, 0, stream>>>(rowptr, cols, level);
    sort_kernel<<<1, 1024, 0, stream>>>(level, perm, lev_p, meta);
    prep_kernel<<<1, 256, 0, stream>>>(lev_p, lstart, bar);
    coef_kernel<<<16, 256, 0, stream>>>(raw_n, raw_q, raw_p, width, length,
                                        slope, x_stor, c1p, c2p, c3p, c4p);
    solve_kernel<<<NBLK, 256, 0, stream>>>(q_prime, c1p, c2p, c3p, c4p, rowptr,
                                           cols, perm, meta, lstart, bar, X, out,
                                           TC, NCH);
}